// Round 11
// baseline (481.504 us; speedup 1.0000x reference)
//
#include <hip/hip_runtime.h>
#include <hip/hip_fp16.h>

#define DEV __device__ __forceinline__

typedef _Float16 f16x8 __attribute__((ext_vector_type(8)));
typedef float f32x4 __attribute__((ext_vector_type(4)));

DEV float mask_val(const unsigned char* mb, int n) {
  // Detect train_mask storage from its first element: uint8 bool / int32 / float32.
  unsigned b0 = mb[0], b1 = mb[1], b2 = mb[2], b3 = mb[3];
  if (b0 <= 1u && b1 == b0 && b2 == b0 && b3 == b0) {
    return mb[n] ? 1.f : 0.f;                       // 1-byte bool
  } else if (b1 == 0u && b2 == 0u && b3 == 0u) {
    return ((const int*)mb)[n] ? 1.f : 0.f;         // int32
  } else {
    return (((const float*)mb)[n] != 0.f) ? 1.f : 0.f; // float32
  }
}

DEV float swz16(float x) {  // xor-16 butterfly step within each 32-lane half
  return __int_as_float(__builtin_amdgcn_ds_swizzle(__float_as_int(x), 0x401F));
}

DEV unsigned pack_h2(float a, float b) {
  __half2 t = __halves2half2(__float2half_rn(a), __float2half_rn(b));
  return *(unsigned*)&t;
}

// ---------------- K0: rank-1 collapses of the context-attention algebra ----------------
__global__ void k_precompute(const float* __restrict__ tf_w, const float* __restrict__ tf_b,
                             const float* __restrict__ deg_w, const float* __restrict__ deg_b,
                             const float* __restrict__ wenc_w, const float* __restrict__ wenc_b,
                             const float* __restrict__ comb_w, float* __restrict__ cbuf) {
  int c = threadIdx.x;  // 64 threads
  float A0 = 0, B0 = 0, A1 = 0, B1 = 0, P0 = 0, Q0 = 0, P1 = 0, Q1 = 0;
  for (int j = 0; j < 64; ++j) {
    float w  = wenc_w[j * 64 + c];
    float cw = comb_w[(64 + j) * 64 + c];
    float twj = tf_w[j], tbj = tf_b[j], dwj = deg_w[j], dbj = deg_b[j];
    A0 += twj * w;  B0 += tbj * w;
    A1 += dwj * w;  B1 += dbj * w;
    P0 += twj * cw; Q0 += tbj * cw;
    P1 += dwj * cw; Q1 += dbj * cw;
  }
  float wb = wenc_b[c];
  cbuf[c]       = A0; cbuf[64 + c]  = B0 + wb;
  cbuf[128 + c] = A1; cbuf[192 + c] = B1 + wb;
  cbuf[256 + c] = P0; cbuf[320 + c] = Q0;
  cbuf[384 + c] = P1; cbuf[448 + c] = Q1;
}

// ---------------- K-wcvt: 5 weights fp32 [k][c] -> fp16 transposed wt[stage][c][k] ----------------
__global__ __launch_bounds__(256) void k_wcvt(
    const float* __restrict__ lin_w, const float* __restrict__ Wq,
    const float* __restrict__ Wk, const float* __restrict__ Wv,
    const float* __restrict__ Wsk, _Float16* __restrict__ wt) {
  const float* Ws[5] = {lin_w, Wq, Wk, Wv, Wsk};
  int idx = blockIdx.x * 256 + threadIdx.x;
  if (idx < 5 * 4096) {
    int s = idx >> 12, r = idx & 4095;
    int j = r >> 6, c = r & 63;
    wt[(s << 12) + c * 64 + j] = (_Float16)Ws[s][j * 64 + c];
  }
}

// ---------------- K1: MFMA node projections (layouts verified in-session R8) ----------------
__global__ __launch_bounds__(256) void k_node_proj(
    const float* __restrict__ x, const _Float16* __restrict__ wt,
    const float* __restrict__ lin_b, const float* __restrict__ bq,
    const float* __restrict__ bk, const float* __restrict__ bv,
    const float* __restrict__ bsk, const float* __restrict__ be,
    float* __restrict__ q, __half2* __restrict__ kvp,
    float* __restrict__ skipout, int N) {
  __shared__ _Float16 H[4][16 * 72];
  const int tid = threadIdx.x;
  const int lane = tid & 63;
  const int wv = tid >> 6;
  const int mrow = lane & 15;
  const int kgrp = lane >> 4;
  const float invs = 0.17677669529663687f;  // 1/sqrt(32)
  float b_lin[4], b_q[4], b_k[4], b_v[4], b_sk[4];
#pragma unroll
  for (int nt = 0; nt < 4; ++nt) {
    const int cc = nt * 16 + mrow;
    b_lin[nt] = lin_b[cc];
    b_q[nt] = bq[cc];
    b_k[nt] = bk[cc] + be[cc];
    b_v[nt] = bv[cc] + be[cc];
    b_sk[nt] = bsk[cc];
  }
  _Float16* Hw = H[wv];
  const int ntiles = (N + 63) >> 6;
  for (int tile = blockIdx.x; tile < ntiles; tile += gridDim.x) {
    const int base = tile << 6;
    const int rowA = base + wv * 16 + mrow;
    const int rclamp = (rowA < N) ? rowA : (N - 1);
    const float* xr = x + (size_t)rclamp * 64 + kgrp * 8;
    const float4 u0 = *(const float4*)xr;
    const float4 u1 = *(const float4*)(xr + 4);
    const float4 u2 = *(const float4*)(xr + 32);
    const float4 u3 = *(const float4*)(xr + 36);
    const f16x8 a0 = {(_Float16)u0.x, (_Float16)u0.y, (_Float16)u0.z, (_Float16)u0.w,
                      (_Float16)u1.x, (_Float16)u1.y, (_Float16)u1.z, (_Float16)u1.w};
    const f16x8 a1 = {(_Float16)u2.x, (_Float16)u2.y, (_Float16)u2.z, (_Float16)u2.w,
                      (_Float16)u3.x, (_Float16)u3.y, (_Float16)u3.z, (_Float16)u3.w};
#pragma unroll
    for (int nt = 0; nt < 4; ++nt) {
      const _Float16* wb0 = wt + (nt * 16 + mrow) * 64 + kgrp * 8;
      const f16x8 B0 = *(const f16x8*)wb0;
      const f16x8 B1 = *(const f16x8*)(wb0 + 32);
      f32x4 C = {0.f, 0.f, 0.f, 0.f};
      C = __builtin_amdgcn_mfma_f32_16x16x32_f16(a0, B0, C, 0, 0, 0);
      C = __builtin_amdgcn_mfma_f32_16x16x32_f16(a1, B1, C, 0, 0, 0);
#pragma unroll
      for (int r = 0; r < 4; ++r) {
        const float hval = fmaxf(C[r] + b_lin[nt], 0.f);
        Hw[(kgrp * 4 + r) * 72 + nt * 16 + mrow] = (_Float16)hval;
      }
    }
    const f16x8 ha0 = *(const f16x8*)(Hw + mrow * 72 + kgrp * 8);
    const f16x8 ha1 = *(const f16x8*)(Hw + mrow * 72 + 32 + kgrp * 8);
    const int orow0 = base + wv * 16 + kgrp * 4;
#pragma unroll
    for (int nt = 0; nt < 4; ++nt) {
      const _Float16* wb0 = wt + 4096 + (nt * 16 + mrow) * 64 + kgrp * 8;
      const f16x8 B0 = *(const f16x8*)wb0;
      const f16x8 B1 = *(const f16x8*)(wb0 + 32);
      f32x4 C = {0.f, 0.f, 0.f, 0.f};
      C = __builtin_amdgcn_mfma_f32_16x16x32_f16(ha0, B0, C, 0, 0, 0);
      C = __builtin_amdgcn_mfma_f32_16x16x32_f16(ha1, B1, C, 0, 0, 0);
#pragma unroll
      for (int r = 0; r < 4; ++r) {
        const int orow = orow0 + r;
        if (orow < N) q[(size_t)orow * 64 + nt * 16 + mrow] = (C[r] + b_q[nt]) * invs;
      }
    }
#pragma unroll
    for (int nt = 0; nt < 4; ++nt) {
      const _Float16* wk0 = wt + 2 * 4096 + (nt * 16 + mrow) * 64 + kgrp * 8;
      const _Float16* wv0 = wt + 3 * 4096 + (nt * 16 + mrow) * 64 + kgrp * 8;
      const f16x8 Bk0 = *(const f16x8*)wk0;
      const f16x8 Bk1 = *(const f16x8*)(wk0 + 32);
      const f16x8 Bv0 = *(const f16x8*)wv0;
      const f16x8 Bv1 = *(const f16x8*)(wv0 + 32);
      f32x4 Ck = {0.f, 0.f, 0.f, 0.f};
      f32x4 Cv = {0.f, 0.f, 0.f, 0.f};
      Ck = __builtin_amdgcn_mfma_f32_16x16x32_f16(ha0, Bk0, Ck, 0, 0, 0);
      Ck = __builtin_amdgcn_mfma_f32_16x16x32_f16(ha1, Bk1, Ck, 0, 0, 0);
      Cv = __builtin_amdgcn_mfma_f32_16x16x32_f16(ha0, Bv0, Cv, 0, 0, 0);
      Cv = __builtin_amdgcn_mfma_f32_16x16x32_f16(ha1, Bv1, Cv, 0, 0, 0);
#pragma unroll
      for (int r = 0; r < 4; ++r) {
        const int orow = orow0 + r;
        if (orow < N)
          kvp[(size_t)orow * 64 + nt * 16 + mrow] =
              __halves2half2(__float2half_rn(Ck[r] + b_k[nt]), __float2half_rn(Cv[r] + b_v[nt]));
      }
    }
#pragma unroll
    for (int nt = 0; nt < 4; ++nt) {
      const _Float16* wb0 = wt + 4 * 4096 + (nt * 16 + mrow) * 64 + kgrp * 8;
      const f16x8 B0 = *(const f16x8*)wb0;
      const f16x8 B1 = *(const f16x8*)(wb0 + 32);
      f32x4 C = {0.f, 0.f, 0.f, 0.f};
      C = __builtin_amdgcn_mfma_f32_16x16x32_f16(ha0, B0, C, 0, 0, 0);
      C = __builtin_amdgcn_mfma_f32_16x16x32_f16(ha1, B1, C, 0, 0, 0);
#pragma unroll
      for (int r = 0; r < 4; ++r) {
        const int orow = orow0 + r;
        if (orow < N) skipout[(size_t)orow * 64 + nt * 16 + mrow] = C[r] + b_sk[nt];
      }
    }
  }
}

// ---------------- CSR build ----------------
__global__ __launch_bounds__(256) void k_hist(const int* __restrict__ ei, int* __restrict__ counts, int E) {
  int i = blockIdx.x * 256 + threadIdx.x;
  if (i < E) atomicAdd(&counts[ei[E + i]], 1);
}

__global__ __launch_bounds__(256) void k_scan1(const int* __restrict__ counts, int* __restrict__ excl,
                                               int* __restrict__ bsum, int N) {
  __shared__ int s[256];
  const int t = threadIdx.x;
  const int idx = blockIdx.x * 256 + t;
  int val = (idx < N) ? counts[idx] : 0;
  s[t] = val;
  __syncthreads();
  for (int d = 1; d < 256; d <<= 1) {
    int add = (t >= d) ? s[t - d] : 0;
    __syncthreads();
    s[t] += add;
    __syncthreads();
  }
  if (idx < N) excl[idx] = s[t] - val;
  if (t == 255) bsum[blockIdx.x] = s[255];
}

__global__ __launch_bounds__(1024) void k_scan2(int* __restrict__ bsum, int B) {
  __shared__ int sm[1024];
  const int t = threadIdx.x;
  if (B <= 1024) {
    int val = (t < B) ? bsum[t] : 0;
    sm[t] = val;
    __syncthreads();
    for (int d = 1; d < 1024; d <<= 1) {
      int add = (t >= d) ? sm[t - d] : 0;
      __syncthreads();
      sm[t] += add;
      __syncthreads();
    }
    if (t < B) bsum[t] = sm[t] - val;  // exclusive
  } else if (t == 0) {
    int acc = 0;
    for (int i = 0; i < B; ++i) { int tt = bsum[i]; bsum[i] = acc; acc += tt; }
  }
}

__global__ __launch_bounds__(256) void k_scan3(const int* __restrict__ bsum, int* __restrict__ rowptr,
                                               int* __restrict__ next, int N, int E) {
  int i = blockIdx.x * 256 + threadIdx.x;
  if (i < N) {
    int r = rowptr[i] + bsum[i >> 8];
    rowptr[i] = r;
    next[i] = r;
  }
  if (i == 0) rowptr[N] = E;
}

__global__ __launch_bounds__(256) void k_fill(const int* __restrict__ ei,
                                              const float* __restrict__ node_time,
                                              const float* __restrict__ edge_time,
                                              int* __restrict__ next, int2* __restrict__ er, int E) {
  int e = blockIdx.x * 256 + threadIdx.x;
  if (e < E) {
    int s = ei[e], d = ei[E + e];
    int pos = atomicAdd(&next[d], 1);
    er[pos] = make_int2(s, __float_as_int(node_time[s] - edge_time[e]));
  }
}

// ---------------- K2: MFMA flash-style CSR aggregate ----------------
// One wave per node (persistent grid). Per 16-edge chunk, staged in WAVE-PRIVATE LDS.
// FIXES vs R9: (1) Vt/Rv K-slices [16,32) zero-initialized once (MFMA B reads them;
// 0xgarbage(Inf/NaN) = NaN); (2) den computed for BOTH heads via masked-exp butterfly
// (A-frag reuse gave head1 lanes head0's den).
__global__ __launch_bounds__(256) void k_aggregate(
    const int* __restrict__ rowptr, const int2* __restrict__ er,
    const float* __restrict__ q, const unsigned* __restrict__ kvu,
    const float* __restrict__ time_w, const float* __restrict__ time_b,
    const float* __restrict__ We,
    float* __restrict__ h1, int N) {
  __shared__ _Float16 KXs[4][16 * 104];  // pitch 104 halfs
  __shared__ _Float16 VTs[4][64 * 40];   // pitch 40
  __shared__ _Float16 RVs[4][32 * 40];
  __shared__ _Float16 QGs[4][128];       // q[0..63] | G[64..127]
  __shared__ _Float16 EAs[4][64];        // ea_h0[0..31] | ea_h1[32..63]; e>=16 stays 0
  __shared__ float swS[4][64];
  const int tid = threadIdx.x;
  const int lane = tid & 63;
  const int wv = tid >> 6;
  const int c = lane;
  const int h32 = c & 32;
  const int mrow = lane & 15;
  const int koff = (lane >> 4) * 8;
  const float INV2PI = 0.15915494309189535f;
  float wcol[32], Gw[32];
#pragma unroll
  for (int j = 0; j < 32; ++j) wcol[j] = We[j * 64 + c];
#pragma unroll
  for (int j = 0; j < 32; ++j) Gw[j] = We[(c & 31) * 64 + h32 + j];
  const float tw = time_w[c & 31] * INV2PI;
  const float tb = time_b[c & 31] * INV2PI;
  _Float16* Kx = KXs[wv];
  _Float16* Vt = VTs[wv];
  _Float16* Rv = RVs[wv];
  _Float16* qg = QGs[wv];
  _Float16* ea = EAs[wv];
  ea[lane] = (_Float16)0.f;  // zero once; writers only touch e<16 of each head
  {  // zero the never-written K in [16,32) B-operand slices (read by PV/S MFMAs)
    const uint4 z = make_uint4(0u, 0u, 0u, 0u);
    *(uint4*)(Vt + lane * 40 + 16) = z;
    *(uint4*)(Vt + lane * 40 + 24) = z;
    if (lane < 32) {
      *(uint4*)(Rv + lane * 40 + 16) = z;
      *(uint4*)(Rv + lane * 40 + 24) = z;
    }
  }
  const int n0 = blockIdx.x * 4 + wv;
  const int nstride = gridDim.x * 4;
  for (int n = n0; n < N; n += nstride) {
    const int start = rowptr[n];
    const int end = rowptr[n + 1];
    const float qc = q[(size_t)n * 64 + c];  // pre-scaled by 1/sqrt(32)
    swS[wv][c] = qc;
    float Gc = 0.f;
#pragma unroll
    for (int j = 0; j < 32; ++j) Gc = fmaf(swS[wv][h32 | j], Gw[j], Gc);
    qg[c] = (_Float16)qc;
    qg[64 + c] = (_Float16)Gc;
    const f16x8 qf0 = *(const f16x8*)&qg[koff];        // q head0 broadcast B-frag
    const f16x8 qf1 = *(const f16x8*)&qg[32 + koff];   // q head1
    const f16x8 gf0 = *(const f16x8*)&qg[64 + koff];   // G head0
    const f16x8 gf1 = *(const f16x8*)&qg[96 + koff];   // G head1
    float m0 = -1e30f, m1 = -1e30f, num = 0.f, S = 0.f, den = 0.f;
    for (int ce = start; ce < end; ce += 16) {
      const int cnt = (end - ce < 16) ? (end - ce) : 16;
      int src_[16];
      float rel_[16];
#pragma unroll
      for (int i = 0; i < 16; ++i) {
        const int ee = ce + ((i < cnt) ? i : cnt - 1);
        const int2 a = er[ee];
        src_[i] = a.x;
        rel_[i] = __int_as_float(a.y);
      }
      unsigned kvr[16];
#pragma unroll
      for (int i = 0; i < 16; ++i) kvr[i] = kvu[(size_t)src_[i] * 64 + c];
      // stage K edge-major (b16 x16) + V chan-major (2x b128)
#pragma unroll
      for (int i = 0; i < 16; ++i) {
        union { unsigned short u; _Float16 h; } cv;
        cv.u = (unsigned short)(kvr[i] & 0xFFFFu);
        Kx[i * 104 + c] = cv.h;
      }
      {
        unsigned vv[8];
#pragma unroll
        for (int j = 0; j < 8; ++j)
          vv[j] = (kvr[2 * j] >> 16) | (kvr[2 * j + 1] & 0xFFFF0000u);
        *(uint4*)(Vt + c * 40) = make_uint4(vv[0], vv[1], vv[2], vv[3]);
        *(uint4*)(Vt + c * 40 + 8) = make_uint4(vv[4], vv[5], vv[6], vv[7]);
      }
      float rv_[16];
#pragma unroll
      for (int i = 0; i < 16; ++i) {
        float ang = fmaf(rel_[i], tw, tb);
        ang = ang - floorf(ang);
        rv_[i] = __builtin_amdgcn_cosf(ang);  // cos(2*pi*ang)
      }
      if (lane < 32) {  // c == j here
#pragma unroll
        for (int i = 0; i < 16; ++i) Kx[i * 104 + 64 + c] = (_Float16)rv_[i];
        unsigned rr[8];
#pragma unroll
        for (int j = 0; j < 8; ++j) rr[j] = pack_h2(rv_[2 * j], rv_[2 * j + 1]);
        *(uint4*)(Rv + c * 40) = make_uint4(rr[0], rr[1], rr[2], rr[3]);
        *(uint4*)(Rv + c * 40 + 8) = make_uint4(rr[4], rr[5], rr[6], rr[7]);
      }
      // ---- QK: alpha_h[e], e = (lane>>4)*4 + reg ----
      const f16x8 Arv = *(const f16x8*)&Kx[mrow * 104 + 64 + koff];
      const f16x8 Ak0 = *(const f16x8*)&Kx[mrow * 104 + koff];
      const f16x8 Ak1 = *(const f16x8*)&Kx[mrow * 104 + 32 + koff];
      f32x4 C0 = {0.f, 0.f, 0.f, 0.f}, C1 = {0.f, 0.f, 0.f, 0.f};
      C0 = __builtin_amdgcn_mfma_f32_16x16x32_f16(Arv, gf0, C0, 0, 0, 0);
      C0 = __builtin_amdgcn_mfma_f32_16x16x32_f16(Ak0, qf0, C0, 0, 0, 0);
      C1 = __builtin_amdgcn_mfma_f32_16x16x32_f16(Arv, gf1, C1, 0, 0, 0);
      C1 = __builtin_amdgcn_mfma_f32_16x16x32_f16(Ak1, qf1, C1, 0, 0, 0);
      // chunk max per head (padded slots duplicate real edges -> max unaffected)
      float x0 = fmaxf(fmaxf(C0[0], C0[1]), fmaxf(C0[2], C0[3]));
      float x1 = fmaxf(fmaxf(C1[0], C1[1]), fmaxf(C1[2], C1[3]));
      x0 = fmaxf(x0, swz16(x0)); x0 = fmaxf(x0, __shfl_xor(x0, 32, 64));
      x1 = fmaxf(x1, swz16(x1)); x1 = fmaxf(x1, __shfl_xor(x1, 32, 64));
      const float mn0 = fmaxf(m0, x0);
      const float mn1 = fmaxf(m1, x1);
      // ea for PV/S A-operand: 16 writer lanes, one edge each; padded edges -> 0
      if (mrow < 4) {
        const int r = lane & 3;
        const int e = (lane >> 4) * 4 + r;
        const float p0 = (r == 0) ? C0[0] : (r == 1) ? C0[1] : (r == 2) ? C0[2] : C0[3];
        const float p1 = (r == 0) ? C1[0] : (r == 1) ? C1[1] : (r == 2) ? C1[2] : C1[3];
        ea[e] = (_Float16)((e < cnt) ? __expf(p0 - mn0) : 0.f);
        ea[32 + e] = (_Float16)((e < cnt) ? __expf(p1 - mn1) : 0.f);
      }
      // dens for BOTH heads via masked exp + butterfly (lane group g holds edges 4g..4g+3)
      float ds0 = 0.f, ds1 = 0.f;
      const int e0i = (lane >> 4) * 4;
#pragma unroll
      for (int r = 0; r < 4; ++r) {
        const bool ok = (e0i + r) < cnt;
        ds0 += ok ? __expf(C0[r] - mn0) : 0.f;
        ds1 += ok ? __expf(C1[r] - mn1) : 0.f;
      }
      ds0 += swz16(ds0); ds0 += __shfl_xor(ds0, 32, 64);
      ds1 += swz16(ds1); ds1 += __shfl_xor(ds1, 32, 64);
      const float ds = h32 ? ds1 : ds0;
      const f16x8 eaf0 = *(const f16x8*)&ea[koff];
      const f16x8 eaf1 = *(const f16x8*)&ea[32 + koff];
      // ---- PV + S (8 MFMAs) ----
      const f16x8 Bv0 = *(const f16x8*)&Vt[(0 + mrow) * 40 + koff];
      const f16x8 Bv1 = *(const f16x8*)&Vt[(16 + mrow) * 40 + koff];
      const f16x8 Bv2 = *(const f16x8*)&Vt[(32 + mrow) * 40 + koff];
      const f16x8 Bv3 = *(const f16x8*)&Vt[(48 + mrow) * 40 + koff];
      const f16x8 Br0 = *(const f16x8*)&Rv[(0 + mrow) * 40 + koff];
      const f16x8 Br1 = *(const f16x8*)&Rv[(16 + mrow) * 40 + koff];
      const f32x4 Z = {0.f, 0.f, 0.f, 0.f};
      const f32x4 N0 = __builtin_amdgcn_mfma_f32_16x16x32_f16(eaf0, Bv0, Z, 0, 0, 0);
      const f32x4 N1 = __builtin_amdgcn_mfma_f32_16x16x32_f16(eaf0, Bv1, Z, 0, 0, 0);
      const f32x4 N2 = __builtin_amdgcn_mfma_f32_16x16x32_f16(eaf1, Bv2, Z, 0, 0, 0);
      const f32x4 N3 = __builtin_amdgcn_mfma_f32_16x16x32_f16(eaf1, Bv3, Z, 0, 0, 0);
      const f32x4 S0 = __builtin_amdgcn_mfma_f32_16x16x32_f16(eaf0, Br0, Z, 0, 0, 0);
      const f32x4 S1 = __builtin_amdgcn_mfma_f32_16x16x32_f16(eaf0, Br1, Z, 0, 0, 0);
      const f32x4 S2 = __builtin_amdgcn_mfma_f32_16x16x32_f16(eaf1, Br0, Z, 0, 0, 0);
      const f32x4 S3 = __builtin_amdgcn_mfma_f32_16x16x32_f16(eaf1, Br1, Z, 0, 0, 0);
      const int sel = (c >> 4) & 3;
      const float nadd = (sel == 0) ? N0[0] : (sel == 1) ? N1[0] : (sel == 2) ? N2[0] : N3[0];
      const float sadd = (sel == 0) ? S0[0] : (sel == 1) ? S1[0] : (sel == 2) ? S2[0] : S3[0];
      const float sc = __expf((h32 ? m1 : m0) - (h32 ? mn1 : mn0));
      num = fmaf(num, sc, nadd);
      S = fmaf(S, sc, sadd);
      den = fmaf(den, sc, ds);
      m0 = mn0;
      m1 = mn1;
    }
    // e-projection contribution: econ[c] = sum_j We[j,c] * S[head(c)*32 + j]
    swS[wv][c] = S;
    float econ = 0.f;
#pragma unroll
    for (int j = 0; j < 32; ++j) econ = fmaf(swS[wv][h32 | j], wcol[j], econ);
    const float agg = (num + econ) / (den + 1e-16f);
    h1[(size_t)n * 64 + c] = agg + h1[(size_t)n * 64 + c];  // + staged skip
  }
}

// ---------------- K4: epilogue (context attention + combine + out + log_softmax) ----------------
__global__ __launch_bounds__(256) void k_epilogue(
    const float* __restrict__ t_int, const float* __restrict__ deg,
    const float* __restrict__ cbuf,
    const float* __restrict__ wx_w, const float* __restrict__ wx_b,
    const float* __restrict__ comb_w, const float* __restrict__ comb_b,
    const float* __restrict__ out_w, const float* __restrict__ out_b,
    const int* __restrict__ y, const unsigned char* __restrict__ maskb,
    float* __restrict__ out, int N) {
  __shared__ float sh[4][64];
  const int tid = threadIdx.x;
  const int c = tid & 63;
  const int wv = tid >> 6;
  float wxreg[64], cbreg[64];
#pragma unroll
  for (int j = 0; j < 64; ++j) { wxreg[j] = wx_w[j * 64 + c]; cbreg[j] = comb_w[j * 64 + c]; }
  const float A0 = cbuf[c], B0 = cbuf[64 + c], A1 = cbuf[128 + c], B1 = cbuf[192 + c];
  const float P0 = cbuf[256 + c], Q0 = cbuf[320 + c], P1 = cbuf[384 + c], Q1 = cbuf[448 + c];
  const float wxb = wx_b[c], cbb = comb_b[c];
  const float ow0 = out_w[c * 2 + 0], ow1 = out_w[c * 2 + 1];
  const float ob0 = out_b[0], ob1 = out_b[1];
  const size_t O1 = (size_t)N * 64;
  const size_t O2 = O1 + (size_t)N * 2;
  const size_t O3 = O2 + (size_t)N;
  const int ngroups = (N + 3) >> 2;
  for (int g = blockIdx.x; g < ngroups; g += gridDim.x) {
    const int n = g * 4 + wv;
    const bool act = n < N;
    float h1a = 0.f, ti = 0.f, dg = 0.f;
    if (act) {
      h1a = out[(size_t)n * 64 + c];
      ti = t_int[n];
      dg = deg[n];
    }
    sh[wv][c] = h1a;
    __syncthreads();
    const float4* hr = (const float4*)&sh[wv][0];
    float xp = wxb;
    float acc = cbb;
#pragma unroll
    for (int j4 = 0; j4 < 16; ++j4) {
      float4 hv = hr[j4];
      xp  = fmaf(hv.x, wxreg[4 * j4 + 0], xp);
      xp  = fmaf(hv.y, wxreg[4 * j4 + 1], xp);
      xp  = fmaf(hv.z, wxreg[4 * j4 + 2], xp);
      xp  = fmaf(hv.w, wxreg[4 * j4 + 3], xp);
      acc = fmaf(hv.x, cbreg[4 * j4 + 0], acc);
      acc = fmaf(hv.y, cbreg[4 * j4 + 1], acc);
      acc = fmaf(hv.z, cbreg[4 * j4 + 2], acc);
      acc = fmaf(hv.w, cbreg[4 * j4 + 3], acc);
    }
    xp = tanhf(xp);
    const float ep0 = tanhf(fmaf(ti, A0, B0));
    const float ep1 = tanhf(fmaf(dg, A1, B1));
    float d0 = ep0 * xp, d1 = ep1 * xp;
#pragma unroll
    for (int msk = 32; msk >= 1; msk >>= 1) { d0 += __shfl_xor(d0, msk, 64); d1 += __shfl_xor(d1, msk, 64); }
    const float mx = fmaxf(d0, d1);
    const float e0 = expf(d0 - mx), e1 = expf(d1 - mx);
    const float sden = e0 + e1;
    const float s0 = e0 / sden, s1 = e1 / sden;
    acc = fmaf(s0, fmaf(ti, P0, Q0), acc);
    acc = fmaf(s1, fmaf(dg, P1, Q1), acc);
    float z0 = acc * ow0, z1 = acc * ow1;
#pragma unroll
    for (int msk = 32; msk >= 1; msk >>= 1) { z0 += __shfl_xor(z0, msk, 64); z1 += __shfl_xor(z1, msk, 64); }
    if (act) {
      out[(size_t)n * 64 + c] = acc;
      if (c == 0) {
        z0 += ob0; z1 += ob1;
        const float mz = fmaxf(z0, z1);
        const float lse = mz + logf(expf(z0 - mz) + expf(z1 - mz));
        out[O1 + (size_t)n * 2 + 0] = z0 - lse;
        out[O1 + (size_t)n * 2 + 1] = z1 - lse;
        out[O2 + (size_t)n] = (float)y[n];
        out[O3 + (size_t)n] = mask_val(maskb, n);
      }
    }
    __syncthreads();
  }
}

extern "C" void kernel_launch(void* const* d_in, const int* in_sizes, int n_in,
                              void* d_out, int out_size, void* d_ws, size_t ws_size,
                              hipStream_t stream) {
  const float* x          = (const float*)d_in[0];
  const int*   ei         = (const int*)d_in[1];
  const float* node_time  = (const float*)d_in[2];
  const float* edge_time  = (const float*)d_in[3];
  const float* nmoti      = (const float*)d_in[4];
  const float* nod        = (const float*)d_in[5];
  const int*   y          = (const int*)d_in[6];
  const unsigned char* mask = (const unsigned char*)d_in[7];
  const float* time_w = (const float*)d_in[8];
  const float* time_b = (const float*)d_in[9];
  const float* tf_w   = (const float*)d_in[10];
  const float* tf_b   = (const float*)d_in[11];
  const float* deg_w  = (const float*)d_in[12];
  const float* deg_b  = (const float*)d_in[13];
  const float* lin_w  = (const float*)d_in[14];
  const float* lin_b  = (const float*)d_in[15];
  const float* Wq     = (const float*)d_in[16];
  const float* bq     = (const float*)d_in[17];
  const float* Wk     = (const float*)d_in[18];
  const float* bk     = (const float*)d_in[19];
  const float* Wv     = (const float*)d_in[20];
  const float* bv     = (const float*)d_in[21];
  const float* We     = (const float*)d_in[22];
  const float* be     = (const float*)d_in[23];
  const float* Wsk    = (const float*)d_in[24];
  const float* bsk    = (const float*)d_in[25];
  const float* wenc_w = (const float*)d_in[26];
  const float* wenc_b = (const float*)d_in[27];
  const float* wx_w   = (const float*)d_in[28];
  const float* wx_b   = (const float*)d_in[29];
  const float* comb_w = (const float*)d_in[30];
  const float* comb_b = (const float*)d_in[31];
  const float* out_w  = (const float*)d_in[32];
  const float* out_b  = (const float*)d_in[33];

  const int N = in_sizes[2];   // node_time
  const int E = in_sizes[3];   // edge_time
  const size_t N64 = (size_t)N * 64;

  float*    q    = (float*)d_ws;
  __half2*  kvp  = (__half2*)(q + N64);       // N64 half2 = N64 * 4B
  int2*     er   = (int2*)((char*)kvp + N64 * sizeof(__half2));
  int*      counts = (int*)(er + E);
  int*      rowptr = counts + N;              // N+1 ints
  int*      next   = rowptr + N + 1;
  int*      bsum   = next + N;                // ceil(N/256) ints (padded)
  float*    cbuf   = (float*)(bsum + 4096);
  _Float16* wt     = (_Float16*)(cbuf + 512); // 5 * 4096 fp16
  float*    outf   = (float*)d_out;
  float*    skip   = outf;  // stage skip in d_out[0:N*64)

  const int B = (N + 255) / 256;

  hipMemsetAsync(counts, 0, (size_t)N * sizeof(int), stream);

  k_precompute<<<1, 64, 0, stream>>>(tf_w, tf_b, deg_w, deg_b, wenc_w, wenc_b, comb_w, cbuf);
  k_wcvt<<<80, 256, 0, stream>>>(lin_w, Wq, Wk, Wv, Wsk, wt);

  const int ntiles = (N + 63) >> 6;
  k_node_proj<<<ntiles, 256, 0, stream>>>(x, wt, lin_b, bq, bk, bv, bsk, be,
                                          q, kvp, skip, N);

  const int EB = (E + 255) / 256;
  k_hist<<<EB, 256, 0, stream>>>(ei, counts, E);
  k_scan1<<<B, 256, 0, stream>>>(counts, rowptr, bsum, N);
  k_scan2<<<1, 1024, 0, stream>>>(bsum, B);
  k_scan3<<<B, 256, 0, stream>>>(bsum, rowptr, next, N, E);
  k_fill<<<EB, 256, 0, stream>>>(ei, node_time, edge_time, next, er, E);

  // persistent grid: 768 blocks = 3 blocks/CU (LDS-limited), fully resident
  int agb = 768;
  if (agb > (N + 3) / 4) agb = (N + 3) / 4;
  k_aggregate<<<agb, 256, 0, stream>>>(rowptr, er, q, (const unsigned*)kvp,
                                       time_w, time_b, We, outf, N);

  k_epilogue<<<2048, 256, 0, stream>>>(nmoti, nod, cbuf, wx_w, wx_b,
                                       comb_w, comb_b, out_w, out_b, y, mask, outf, N);
}

// Round 12
// 456.241 us; speedup vs baseline: 1.0554x; 1.0554x over previous
//
#include <hip/hip_runtime.h>
#include <hip/hip_fp16.h>

#define DEV __device__ __forceinline__

typedef _Float16 f16x8 __attribute__((ext_vector_type(8)));
typedef float f32x4 __attribute__((ext_vector_type(4)));

DEV float mask_val(const unsigned char* mb, int n) {
  // Detect train_mask storage from its first element: uint8 bool / int32 / float32.
  unsigned b0 = mb[0], b1 = mb[1], b2 = mb[2], b3 = mb[3];
  if (b0 <= 1u && b1 == b0 && b2 == b0 && b3 == b0) {
    return mb[n] ? 1.f : 0.f;                       // 1-byte bool
  } else if (b1 == 0u && b2 == 0u && b3 == 0u) {
    return ((const int*)mb)[n] ? 1.f : 0.f;         // int32
  } else {
    return (((const float*)mb)[n] != 0.f) ? 1.f : 0.f; // float32
  }
}

DEV float swz16(float x) {  // xor-16 butterfly step within each 32-lane half
  return __int_as_float(__builtin_amdgcn_ds_swizzle(__float_as_int(x), 0x401F));
}

// ---------------- K0: rank-1 collapses of the context-attention algebra ----------------
__global__ void k_precompute(const float* __restrict__ tf_w, const float* __restrict__ tf_b,
                             const float* __restrict__ deg_w, const float* __restrict__ deg_b,
                             const float* __restrict__ wenc_w, const float* __restrict__ wenc_b,
                             const float* __restrict__ comb_w, float* __restrict__ cbuf) {
  int c = threadIdx.x;  // 64 threads
  float A0 = 0, B0 = 0, A1 = 0, B1 = 0, P0 = 0, Q0 = 0, P1 = 0, Q1 = 0;
  for (int j = 0; j < 64; ++j) {
    float w  = wenc_w[j * 64 + c];
    float cw = comb_w[(64 + j) * 64 + c];
    float twj = tf_w[j], tbj = tf_b[j], dwj = deg_w[j], dbj = deg_b[j];
    A0 += twj * w;  B0 += tbj * w;
    A1 += dwj * w;  B1 += dbj * w;
    P0 += twj * cw; Q0 += tbj * cw;
    P1 += dwj * cw; Q1 += dbj * cw;
  }
  float wb = wenc_b[c];
  cbuf[c]       = A0; cbuf[64 + c]  = B0 + wb;
  cbuf[128 + c] = A1; cbuf[192 + c] = B1 + wb;
  cbuf[256 + c] = P0; cbuf[320 + c] = Q0;
  cbuf[384 + c] = P1; cbuf[448 + c] = Q1;
}

// ---------------- K-wcvt: 5 weights fp32 [k][c] -> fp16 transposed wt[stage][c][k] ----------------
__global__ __launch_bounds__(256) void k_wcvt(
    const float* __restrict__ lin_w, const float* __restrict__ Wq,
    const float* __restrict__ Wk, const float* __restrict__ Wv,
    const float* __restrict__ Wsk, _Float16* __restrict__ wt) {
  const float* Ws[5] = {lin_w, Wq, Wk, Wv, Wsk};
  int idx = blockIdx.x * 256 + threadIdx.x;
  if (idx < 5 * 4096) {
    int s = idx >> 12, r = idx & 4095;
    int j = r >> 6, c = r & 63;
    wt[(s << 12) + c * 64 + j] = (_Float16)Ws[s][j * 64 + c];
  }
}

// ---------------- K1: MFMA node projections (layouts verified in-session R8) ----------------
__global__ __launch_bounds__(256) void k_node_proj(
    const float* __restrict__ x, const _Float16* __restrict__ wt,
    const float* __restrict__ lin_b, const float* __restrict__ bq,
    const float* __restrict__ bk, const float* __restrict__ bv,
    const float* __restrict__ bsk, const float* __restrict__ be,
    float* __restrict__ q, __half2* __restrict__ kvp,
    float* __restrict__ skipout, int N) {
  __shared__ _Float16 H[4][16 * 72];
  const int tid = threadIdx.x;
  const int lane = tid & 63;
  const int wv = tid >> 6;
  const int mrow = lane & 15;
  const int kgrp = lane >> 4;
  const float invs = 0.17677669529663687f;  // 1/sqrt(32)
  float b_lin[4], b_q[4], b_k[4], b_v[4], b_sk[4];
#pragma unroll
  for (int nt = 0; nt < 4; ++nt) {
    const int cc = nt * 16 + mrow;
    b_lin[nt] = lin_b[cc];
    b_q[nt] = bq[cc];
    b_k[nt] = bk[cc] + be[cc];
    b_v[nt] = bv[cc] + be[cc];
    b_sk[nt] = bsk[cc];
  }
  _Float16* Hw = H[wv];
  const int ntiles = (N + 63) >> 6;
  for (int tile = blockIdx.x; tile < ntiles; tile += gridDim.x) {
    const int base = tile << 6;
    const int rowA = base + wv * 16 + mrow;
    const int rclamp = (rowA < N) ? rowA : (N - 1);
    const float* xr = x + (size_t)rclamp * 64 + kgrp * 8;
    const float4 u0 = *(const float4*)xr;
    const float4 u1 = *(const float4*)(xr + 4);
    const float4 u2 = *(const float4*)(xr + 32);
    const float4 u3 = *(const float4*)(xr + 36);
    const f16x8 a0 = {(_Float16)u0.x, (_Float16)u0.y, (_Float16)u0.z, (_Float16)u0.w,
                      (_Float16)u1.x, (_Float16)u1.y, (_Float16)u1.z, (_Float16)u1.w};
    const f16x8 a1 = {(_Float16)u2.x, (_Float16)u2.y, (_Float16)u2.z, (_Float16)u2.w,
                      (_Float16)u3.x, (_Float16)u3.y, (_Float16)u3.z, (_Float16)u3.w};
#pragma unroll
    for (int nt = 0; nt < 4; ++nt) {
      const _Float16* wb0 = wt + (nt * 16 + mrow) * 64 + kgrp * 8;
      const f16x8 B0 = *(const f16x8*)wb0;
      const f16x8 B1 = *(const f16x8*)(wb0 + 32);
      f32x4 C = {0.f, 0.f, 0.f, 0.f};
      C = __builtin_amdgcn_mfma_f32_16x16x32_f16(a0, B0, C, 0, 0, 0);
      C = __builtin_amdgcn_mfma_f32_16x16x32_f16(a1, B1, C, 0, 0, 0);
#pragma unroll
      for (int r = 0; r < 4; ++r) {
        const float hval = fmaxf(C[r] + b_lin[nt], 0.f);
        Hw[(kgrp * 4 + r) * 72 + nt * 16 + mrow] = (_Float16)hval;
      }
    }
    const f16x8 ha0 = *(const f16x8*)(Hw + mrow * 72 + kgrp * 8);
    const f16x8 ha1 = *(const f16x8*)(Hw + mrow * 72 + 32 + kgrp * 8);
    const int orow0 = base + wv * 16 + kgrp * 4;
#pragma unroll
    for (int nt = 0; nt < 4; ++nt) {
      const _Float16* wb0 = wt + 4096 + (nt * 16 + mrow) * 64 + kgrp * 8;
      const f16x8 B0 = *(const f16x8*)wb0;
      const f16x8 B1 = *(const f16x8*)(wb0 + 32);
      f32x4 C = {0.f, 0.f, 0.f, 0.f};
      C = __builtin_amdgcn_mfma_f32_16x16x32_f16(ha0, B0, C, 0, 0, 0);
      C = __builtin_amdgcn_mfma_f32_16x16x32_f16(ha1, B1, C, 0, 0, 0);
#pragma unroll
      for (int r = 0; r < 4; ++r) {
        const int orow = orow0 + r;
        if (orow < N) q[(size_t)orow * 64 + nt * 16 + mrow] = (C[r] + b_q[nt]) * invs;
      }
    }
#pragma unroll
    for (int nt = 0; nt < 4; ++nt) {
      const _Float16* wk0 = wt + 2 * 4096 + (nt * 16 + mrow) * 64 + kgrp * 8;
      const _Float16* wv0 = wt + 3 * 4096 + (nt * 16 + mrow) * 64 + kgrp * 8;
      const f16x8 Bk0 = *(const f16x8*)wk0;
      const f16x8 Bk1 = *(const f16x8*)(wk0 + 32);
      const f16x8 Bv0 = *(const f16x8*)wv0;
      const f16x8 Bv1 = *(const f16x8*)(wv0 + 32);
      f32x4 Ck = {0.f, 0.f, 0.f, 0.f};
      f32x4 Cv = {0.f, 0.f, 0.f, 0.f};
      Ck = __builtin_amdgcn_mfma_f32_16x16x32_f16(ha0, Bk0, Ck, 0, 0, 0);
      Ck = __builtin_amdgcn_mfma_f32_16x16x32_f16(ha1, Bk1, Ck, 0, 0, 0);
      Cv = __builtin_amdgcn_mfma_f32_16x16x32_f16(ha0, Bv0, Cv, 0, 0, 0);
      Cv = __builtin_amdgcn_mfma_f32_16x16x32_f16(ha1, Bv1, Cv, 0, 0, 0);
#pragma unroll
      for (int r = 0; r < 4; ++r) {
        const int orow = orow0 + r;
        if (orow < N)
          kvp[(size_t)orow * 64 + nt * 16 + mrow] =
              __halves2half2(__float2half_rn(Ck[r] + b_k[nt]), __float2half_rn(Cv[r] + b_v[nt]));
      }
    }
#pragma unroll
    for (int nt = 0; nt < 4; ++nt) {
      const _Float16* wb0 = wt + 4 * 4096 + (nt * 16 + mrow) * 64 + kgrp * 8;
      const f16x8 B0 = *(const f16x8*)wb0;
      const f16x8 B1 = *(const f16x8*)(wb0 + 32);
      f32x4 C = {0.f, 0.f, 0.f, 0.f};
      C = __builtin_amdgcn_mfma_f32_16x16x32_f16(ha0, B0, C, 0, 0, 0);
      C = __builtin_amdgcn_mfma_f32_16x16x32_f16(ha1, B1, C, 0, 0, 0);
#pragma unroll
      for (int r = 0; r < 4; ++r) {
        const int orow = orow0 + r;
        if (orow < N) skipout[(size_t)orow * 64 + nt * 16 + mrow] = C[r] + b_sk[nt];
      }
    }
  }
}

// ---------------- CSR build ----------------
__global__ __launch_bounds__(256) void k_hist(const int* __restrict__ ei, int* __restrict__ counts, int E) {
  int i = blockIdx.x * 256 + threadIdx.x;
  if (i < E) atomicAdd(&counts[ei[E + i]], 1);
}

__global__ __launch_bounds__(256) void k_scan1(const int* __restrict__ counts, int* __restrict__ excl,
                                               int* __restrict__ bsum, int N) {
  __shared__ int s[256];
  const int t = threadIdx.x;
  const int idx = blockIdx.x * 256 + t;
  int val = (idx < N) ? counts[idx] : 0;
  s[t] = val;
  __syncthreads();
  for (int d = 1; d < 256; d <<= 1) {
    int add = (t >= d) ? s[t - d] : 0;
    __syncthreads();
    s[t] += add;
    __syncthreads();
  }
  if (idx < N) excl[idx] = s[t] - val;
  if (t == 255) bsum[blockIdx.x] = s[255];
}

__global__ __launch_bounds__(1024) void k_scan2(int* __restrict__ bsum, int B) {
  __shared__ int sm[1024];
  const int t = threadIdx.x;
  if (B <= 1024) {
    int val = (t < B) ? bsum[t] : 0;
    sm[t] = val;
    __syncthreads();
    for (int d = 1; d < 1024; d <<= 1) {
      int add = (t >= d) ? sm[t - d] : 0;
      __syncthreads();
      sm[t] += add;
      __syncthreads();
    }
    if (t < B) bsum[t] = sm[t] - val;  // exclusive
  } else if (t == 0) {
    int acc = 0;
    for (int i = 0; i < B; ++i) { int tt = bsum[i]; bsum[i] = acc; acc += tt; }
  }
}

__global__ __launch_bounds__(256) void k_scan3(const int* __restrict__ bsum, int* __restrict__ rowptr,
                                               int* __restrict__ next, int N, int E) {
  int i = blockIdx.x * 256 + threadIdx.x;
  if (i < N) {
    int r = rowptr[i] + bsum[i >> 8];
    rowptr[i] = r;
    next[i] = r;
  }
  if (i == 0) rowptr[N] = E;
}

__global__ __launch_bounds__(256) void k_fill(const int* __restrict__ ei,
                                              const float* __restrict__ node_time,
                                              const float* __restrict__ edge_time,
                                              int* __restrict__ next, int2* __restrict__ er, int E) {
  int e = blockIdx.x * 256 + threadIdx.x;
  if (e < E) {
    int s = ei[e], d = ei[E + e];
    int pos = atomicAdd(&next[d], 1);
    er[pos] = make_int2(s, __float_as_int(node_time[s] - edge_time[e]));
  }
}

// ---------------- K2: hybrid CSR aggregate ----------------
// QK via MFMA (R11-verified path: Kx staging, q/G B-frags, max-reduce, 16 writer-lane exps)
// but ea stored as FP32 in LDS and PV/S/den done per-lane from registers (R8-style) —
// no Vt/Rv staging (that was the 3.7M bank conflicts + 46KB LDS in R11).
__global__ __launch_bounds__(256) void k_aggregate(
    const int* __restrict__ rowptr, const int2* __restrict__ er,
    const float* __restrict__ q, const unsigned* __restrict__ kvu,
    const float* __restrict__ time_w, const float* __restrict__ time_b,
    const float* __restrict__ We,
    float* __restrict__ h1, int N) {
  __shared__ _Float16 KXs[4][16 * 104];  // pitch 104 halfs = 208B: 2-way max on reads (free)
  __shared__ _Float16 QGs[4][128];       // q[0..63] | G[64..127]
  __shared__ float EAs[4][2][16];        // fp32 ea per head per edge
  __shared__ float swS[4][64];
  const int tid = threadIdx.x;
  const int lane = tid & 63;
  const int wv = tid >> 6;
  const int c = lane;
  const int h32 = c & 32;
  const int mrow = lane & 15;
  const int koff = (lane >> 4) * 8;
  const float INV2PI = 0.15915494309189535f;
  float wcol[32], Gw[32];
#pragma unroll
  for (int j = 0; j < 32; ++j) wcol[j] = We[j * 64 + c];
#pragma unroll
  for (int j = 0; j < 32; ++j) Gw[j] = We[(c & 31) * 64 + h32 + j];
  const float tw = time_w[c & 31] * INV2PI;
  const float tb = time_b[c & 31] * INV2PI;
  _Float16* Kx = KXs[wv];
  _Float16* qg = QGs[wv];
  float (*eaF)[16] = EAs[wv];
  const int n0 = blockIdx.x * 4 + wv;
  const int nstride = gridDim.x * 4;
  for (int n = n0; n < N; n += nstride) {
    const int start = rowptr[n];
    const int end = rowptr[n + 1];
    const float skipv = h1[(size_t)n * 64 + c];  // prefetch staged skip early
    const float qc = q[(size_t)n * 64 + c];      // pre-scaled by 1/sqrt(32)
    swS[wv][c] = qc;
    float Gc = 0.f;
#pragma unroll
    for (int j = 0; j < 32; ++j) Gc = fmaf(swS[wv][h32 | j], Gw[j], Gc);
    qg[c] = (_Float16)qc;
    qg[64 + c] = (_Float16)Gc;
    const f16x8 qf0 = *(const f16x8*)&qg[koff];        // q head0 broadcast B-frag
    const f16x8 qf1 = *(const f16x8*)&qg[32 + koff];   // q head1
    const f16x8 gf0 = *(const f16x8*)&qg[64 + koff];   // G head0
    const f16x8 gf1 = *(const f16x8*)&qg[96 + koff];   // G head1
    float m0 = -1e30f, m1 = -1e30f, num = 0.f, S = 0.f, den = 0.f;
    for (int ce = start; ce < end; ce += 16) {
      const int cnt = (end - ce < 16) ? (end - ce) : 16;
      int src_[16];
      float rel_[16];
#pragma unroll
      for (int i = 0; i < 16; ++i) {
        const int ee = ce + ((i < cnt) ? i : cnt - 1);
        const int2 a = er[ee];
        src_[i] = a.x;
        rel_[i] = __int_as_float(a.y);
      }
      unsigned kvr[16];
#pragma unroll
      for (int i = 0; i < 16; ++i) kvr[i] = kvu[(size_t)src_[i] * 64 + c];
      // stage K edge-major (A-operand of QK)
#pragma unroll
      for (int i = 0; i < 16; ++i) {
        union { unsigned short u; _Float16 h; } cv;
        cv.u = (unsigned short)(kvr[i] & 0xFFFFu);
        Kx[i * 104 + c] = cv.h;
      }
      float rv_[16];
#pragma unroll
      for (int i = 0; i < 16; ++i) {
        float ang = fmaf(rel_[i], tw, tb);
        ang = ang - floorf(ang);
        rv_[i] = __builtin_amdgcn_cosf(ang);  // cos(2*pi*ang)
      }
      if (lane < 32) {  // c == j here
#pragma unroll
        for (int i = 0; i < 16; ++i) Kx[i * 104 + 64 + c] = (_Float16)rv_[i];
      }
      // ---- QK via MFMA: alpha_h[e], e = (lane>>4)*4 + reg (R11-verified) ----
      const f16x8 Arv = *(const f16x8*)&Kx[mrow * 104 + 64 + koff];
      const f16x8 Ak0 = *(const f16x8*)&Kx[mrow * 104 + koff];
      const f16x8 Ak1 = *(const f16x8*)&Kx[mrow * 104 + 32 + koff];
      f32x4 C0 = {0.f, 0.f, 0.f, 0.f}, C1 = {0.f, 0.f, 0.f, 0.f};
      C0 = __builtin_amdgcn_mfma_f32_16x16x32_f16(Arv, gf0, C0, 0, 0, 0);
      C0 = __builtin_amdgcn_mfma_f32_16x16x32_f16(Ak0, qf0, C0, 0, 0, 0);
      C1 = __builtin_amdgcn_mfma_f32_16x16x32_f16(Arv, gf1, C1, 0, 0, 0);
      C1 = __builtin_amdgcn_mfma_f32_16x16x32_f16(Ak1, qf1, C1, 0, 0, 0);
      // chunk max per head (padded slots duplicate real edges -> max unaffected)
      float x0 = fmaxf(fmaxf(C0[0], C0[1]), fmaxf(C0[2], C0[3]));
      float x1 = fmaxf(fmaxf(C1[0], C1[1]), fmaxf(C1[2], C1[3]));
      x0 = fmaxf(x0, swz16(x0)); x0 = fmaxf(x0, __shfl_xor(x0, 32, 64));
      x1 = fmaxf(x1, swz16(x1)); x1 = fmaxf(x1, __shfl_xor(x1, 32, 64));
      const float mn0 = fmaxf(m0, x0);
      const float mn1 = fmaxf(m1, x1);
      // ea (fp32): 16 writer lanes, one edge each; padded edges -> 0
      if (mrow < 4) {
        const int r = lane & 3;
        const int e = (lane >> 4) * 4 + r;
        const float p0 = (r == 0) ? C0[0] : (r == 1) ? C0[1] : (r == 2) ? C0[2] : C0[3];
        const float p1 = (r == 0) ? C1[0] : (r == 1) ? C1[1] : (r == 2) ? C1[2] : C1[3];
        eaF[0][e] = (e < cnt) ? __expf(p0 - mn0) : 0.f;
        eaF[1][e] = (e < cnt) ? __expf(p1 - mn1) : 0.f;
      }
      // ---- pass 2 per-lane: rescale then accumulate num/S/den from regs + ea broadcast ----
      const float sc = __expf((h32 ? m1 : m0) - (h32 ? mn1 : mn0));
      num *= sc; S *= sc; den *= sc;
      const float* eah = eaF[h32 ? 1 : 0];
#pragma unroll
      for (int i = 0; i < 16; ++i) {
        if (i < cnt) {
          const float eai = eah[i];  // LDS broadcast (uniform per half-wave)
          const __half2 h2 = *(const __half2*)&kvr[i];
          num = fmaf(eai, __half2float(h2.y), num);
          S = fmaf(eai, rv_[i], S);
          den += eai;
        }
      }
      m0 = mn0;
      m1 = mn1;
    }
    // e-projection contribution: econ[c] = sum_j We[j,c] * S[head(c)*32 + j]
    swS[wv][c] = S;
    float econ = 0.f;
#pragma unroll
    for (int j = 0; j < 32; ++j) econ = fmaf(swS[wv][h32 | j], wcol[j], econ);
    const float agg = (num + econ) / (den + 1e-16f);
    h1[(size_t)n * 64 + c] = agg + skipv;
  }
}

// ---------------- K4: epilogue (context attention + combine + out + log_softmax) ----------------
__global__ __launch_bounds__(256) void k_epilogue(
    const float* __restrict__ t_int, const float* __restrict__ deg,
    const float* __restrict__ cbuf,
    const float* __restrict__ wx_w, const float* __restrict__ wx_b,
    const float* __restrict__ comb_w, const float* __restrict__ comb_b,
    const float* __restrict__ out_w, const float* __restrict__ out_b,
    const int* __restrict__ y, const unsigned char* __restrict__ maskb,
    float* __restrict__ out, int N) {
  __shared__ float sh[4][64];
  const int tid = threadIdx.x;
  const int c = tid & 63;
  const int wv = tid >> 6;
  float wxreg[64], cbreg[64];
#pragma unroll
  for (int j = 0; j < 64; ++j) { wxreg[j] = wx_w[j * 64 + c]; cbreg[j] = comb_w[j * 64 + c]; }
  const float A0 = cbuf[c], B0 = cbuf[64 + c], A1 = cbuf[128 + c], B1 = cbuf[192 + c];
  const float P0 = cbuf[256 + c], Q0 = cbuf[320 + c], P1 = cbuf[384 + c], Q1 = cbuf[448 + c];
  const float wxb = wx_b[c], cbb = comb_b[c];
  const float ow0 = out_w[c * 2 + 0], ow1 = out_w[c * 2 + 1];
  const float ob0 = out_b[0], ob1 = out_b[1];
  const size_t O1 = (size_t)N * 64;
  const size_t O2 = O1 + (size_t)N * 2;
  const size_t O3 = O2 + (size_t)N;
  const int ngroups = (N + 3) >> 2;
  for (int g = blockIdx.x; g < ngroups; g += gridDim.x) {
    const int n = g * 4 + wv;
    const bool act = n < N;
    float h1a = 0.f, ti = 0.f, dg = 0.f;
    if (act) {
      h1a = out[(size_t)n * 64 + c];
      ti = t_int[n];
      dg = deg[n];
    }
    sh[wv][c] = h1a;
    __syncthreads();
    const float4* hr = (const float4*)&sh[wv][0];
    float xp = wxb;
    float acc = cbb;
#pragma unroll
    for (int j4 = 0; j4 < 16; ++j4) {
      float4 hv = hr[j4];
      xp  = fmaf(hv.x, wxreg[4 * j4 + 0], xp);
      xp  = fmaf(hv.y, wxreg[4 * j4 + 1], xp);
      xp  = fmaf(hv.z, wxreg[4 * j4 + 2], xp);
      xp  = fmaf(hv.w, wxreg[4 * j4 + 3], xp);
      acc = fmaf(hv.x, cbreg[4 * j4 + 0], acc);
      acc = fmaf(hv.y, cbreg[4 * j4 + 1], acc);
      acc = fmaf(hv.z, cbreg[4 * j4 + 2], acc);
      acc = fmaf(hv.w, cbreg[4 * j4 + 3], acc);
    }
    xp = tanhf(xp);
    const float ep0 = tanhf(fmaf(ti, A0, B0));
    const float ep1 = tanhf(fmaf(dg, A1, B1));
    float d0 = ep0 * xp, d1 = ep1 * xp;
#pragma unroll
    for (int msk = 32; msk >= 1; msk >>= 1) { d0 += __shfl_xor(d0, msk, 64); d1 += __shfl_xor(d1, msk, 64); }
    const float mx = fmaxf(d0, d1);
    const float e0 = expf(d0 - mx), e1 = expf(d1 - mx);
    const float sden = e0 + e1;
    const float s0 = e0 / sden, s1 = e1 / sden;
    acc = fmaf(s0, fmaf(ti, P0, Q0), acc);
    acc = fmaf(s1, fmaf(dg, P1, Q1), acc);
    float z0 = acc * ow0, z1 = acc * ow1;
#pragma unroll
    for (int msk = 32; msk >= 1; msk >>= 1) { z0 += __shfl_xor(z0, msk, 64); z1 += __shfl_xor(z1, msk, 64); }
    if (act) {
      out[(size_t)n * 64 + c] = acc;
      if (c == 0) {
        z0 += ob0; z1 += ob1;
        const float mz = fmaxf(z0, z1);
        const float lse = mz + logf(expf(z0 - mz) + expf(z1 - mz));
        out[O1 + (size_t)n * 2 + 0] = z0 - lse;
        out[O1 + (size_t)n * 2 + 1] = z1 - lse;
        out[O2 + (size_t)n] = (float)y[n];
        out[O3 + (size_t)n] = mask_val(maskb, n);
      }
    }
    __syncthreads();
  }
}

extern "C" void kernel_launch(void* const* d_in, const int* in_sizes, int n_in,
                              void* d_out, int out_size, void* d_ws, size_t ws_size,
                              hipStream_t stream) {
  const float* x          = (const float*)d_in[0];
  const int*   ei         = (const int*)d_in[1];
  const float* node_time  = (const float*)d_in[2];
  const float* edge_time  = (const float*)d_in[3];
  const float* nmoti      = (const float*)d_in[4];
  const float* nod        = (const float*)d_in[5];
  const int*   y          = (const int*)d_in[6];
  const unsigned char* mask = (const unsigned char*)d_in[7];
  const float* time_w = (const float*)d_in[8];
  const float* time_b = (const float*)d_in[9];
  const float* tf_w   = (const float*)d_in[10];
  const float* tf_b   = (const float*)d_in[11];
  const float* deg_w  = (const float*)d_in[12];
  const float* deg_b  = (const float*)d_in[13];
  const float* lin_w  = (const float*)d_in[14];
  const float* lin_b  = (const float*)d_in[15];
  const float* Wq     = (const float*)d_in[16];
  const float* bq     = (const float*)d_in[17];
  const float* Wk     = (const float*)d_in[18];
  const float* bk     = (const float*)d_in[19];
  const float* Wv     = (const float*)d_in[20];
  const float* bv     = (const float*)d_in[21];
  const float* We     = (const float*)d_in[22];
  const float* be     = (const float*)d_in[23];
  const float* Wsk    = (const float*)d_in[24];
  const float* bsk    = (const float*)d_in[25];
  const float* wenc_w = (const float*)d_in[26];
  const float* wenc_b = (const float*)d_in[27];
  const float* wx_w   = (const float*)d_in[28];
  const float* wx_b   = (const float*)d_in[29];
  const float* comb_w = (const float*)d_in[30];
  const float* comb_b = (const float*)d_in[31];
  const float* out_w  = (const float*)d_in[32];
  const float* out_b  = (const float*)d_in[33];

  const int N = in_sizes[2];   // node_time
  const int E = in_sizes[3];   // edge_time
  const size_t N64 = (size_t)N * 64;

  float*    q    = (float*)d_ws;
  __half2*  kvp  = (__half2*)(q + N64);       // N64 half2 = N64 * 4B
  int2*     er   = (int2*)((char*)kvp + N64 * sizeof(__half2));
  int*      counts = (int*)(er + E);
  int*      rowptr = counts + N;              // N+1 ints
  int*      next   = rowptr + N + 1;
  int*      bsum   = next + N;                // ceil(N/256) ints (padded)
  float*    cbuf   = (float*)(bsum + 4096);
  _Float16* wt     = (_Float16*)(cbuf + 512); // 5 * 4096 fp16
  float*    outf   = (float*)d_out;
  float*    skip   = outf;  // stage skip in d_out[0:N*64)

  const int B = (N + 255) / 256;

  hipMemsetAsync(counts, 0, (size_t)N * sizeof(int), stream);

  k_precompute<<<1, 64, 0, stream>>>(tf_w, tf_b, deg_w, deg_b, wenc_w, wenc_b, comb_w, cbuf);
  k_wcvt<<<80, 256, 0, stream>>>(lin_w, Wq, Wk, Wv, Wsk, wt);

  const int ntiles = (N + 63) >> 6;
  k_node_proj<<<ntiles, 256, 0, stream>>>(x, wt, lin_b, bq, bk, bv, bsk, be,
                                          q, kvp, skip, N);

  const int EB = (E + 255) / 256;
  k_hist<<<EB, 256, 0, stream>>>(ei, counts, E);
  k_scan1<<<B, 256, 0, stream>>>(counts, rowptr, bsum, N);
  k_scan2<<<1, 1024, 0, stream>>>(bsum, B);
  k_scan3<<<B, 256, 0, stream>>>(bsum, rowptr, next, N, E);
  k_fill<<<EB, 256, 0, stream>>>(ei, node_time, edge_time, next, er, E);

  // persistent grid: 768 blocks = 3 blocks/CU, fully resident
  int agb = 768;
  if (agb > (N + 3) / 4) agb = (N + 3) / 4;
  k_aggregate<<<agb, 256, 0, stream>>>(rowptr, er, q, (const unsigned*)kvp,
                                       time_w, time_b, We, outf, N);

  k_epilogue<<<2048, 256, 0, stream>>>(nmoti, nod, cbuf, wx_w, wx_b,
                                       comb_w, comb_b, out_w, out_b, y, mask, outf, N);
}

// Round 13
// 432.688 us; speedup vs baseline: 1.1128x; 1.0544x over previous
//
#include <hip/hip_runtime.h>
#include <hip/hip_fp16.h>

#define DEV __device__ __forceinline__

typedef _Float16 f16x8 __attribute__((ext_vector_type(8)));
typedef float f32x4 __attribute__((ext_vector_type(4)));

DEV float mask_val(const unsigned char* mb, int n) {
  // Detect train_mask storage from its first element: uint8 bool / int32 / float32.
  unsigned b0 = mb[0], b1 = mb[1], b2 = mb[2], b3 = mb[3];
  if (b0 <= 1u && b1 == b0 && b2 == b0 && b3 == b0) {
    return mb[n] ? 1.f : 0.f;                       // 1-byte bool
  } else if (b1 == 0u && b2 == 0u && b3 == 0u) {
    return ((const int*)mb)[n] ? 1.f : 0.f;         // int32
  } else {
    return (((const float*)mb)[n] != 0.f) ? 1.f : 0.f; // float32
  }
}

// sum across each 32-lane half, result in ALL lanes of the half.
// 4 DPP ring-rotation adds within the 16-lane row (VALU pipe, full rate:
// offsets {8,4,2,1} reach all 16 lanes) + one xor-16 ds_swizzle to cross rows.
DEV float hsum32_dpp(float x) {
  int xi;
  xi = __builtin_amdgcn_update_dpp(0, __float_as_int(x), 0x128, 0xF, 0xF, true);  // row_ror:8
  x += __int_as_float(xi);
  xi = __builtin_amdgcn_update_dpp(0, __float_as_int(x), 0x124, 0xF, 0xF, true);  // row_ror:4
  x += __int_as_float(xi);
  xi = __builtin_amdgcn_update_dpp(0, __float_as_int(x), 0x122, 0xF, 0xF, true);  // row_ror:2
  x += __int_as_float(xi);
  xi = __builtin_amdgcn_update_dpp(0, __float_as_int(x), 0x121, 0xF, 0xF, true);  // row_ror:1
  x += __int_as_float(xi);
  x += __int_as_float(__builtin_amdgcn_ds_swizzle(__float_as_int(x), 0x401F));    // xor 16
  return x;
}

// ---------------- K0: rank-1 collapses of the context-attention algebra ----------------
__global__ void k_precompute(const float* __restrict__ tf_w, const float* __restrict__ tf_b,
                             const float* __restrict__ deg_w, const float* __restrict__ deg_b,
                             const float* __restrict__ wenc_w, const float* __restrict__ wenc_b,
                             const float* __restrict__ comb_w, float* __restrict__ cbuf) {
  int c = threadIdx.x;  // 64 threads
  float A0 = 0, B0 = 0, A1 = 0, B1 = 0, P0 = 0, Q0 = 0, P1 = 0, Q1 = 0;
  for (int j = 0; j < 64; ++j) {
    float w  = wenc_w[j * 64 + c];
    float cw = comb_w[(64 + j) * 64 + c];
    float twj = tf_w[j], tbj = tf_b[j], dwj = deg_w[j], dbj = deg_b[j];
    A0 += twj * w;  B0 += tbj * w;
    A1 += dwj * w;  B1 += dbj * w;
    P0 += twj * cw; Q0 += tbj * cw;
    P1 += dwj * cw; Q1 += dbj * cw;
  }
  float wb = wenc_b[c];
  cbuf[c]       = A0; cbuf[64 + c]  = B0 + wb;
  cbuf[128 + c] = A1; cbuf[192 + c] = B1 + wb;
  cbuf[256 + c] = P0; cbuf[320 + c] = Q0;
  cbuf[384 + c] = P1; cbuf[448 + c] = Q1;
}

// ---------------- K-wcvt: 5 weights fp32 [k][c] -> fp16 transposed wt[stage][c][k] ----------------
__global__ __launch_bounds__(256) void k_wcvt(
    const float* __restrict__ lin_w, const float* __restrict__ Wq,
    const float* __restrict__ Wk, const float* __restrict__ Wv,
    const float* __restrict__ Wsk, _Float16* __restrict__ wt) {
  const float* Ws[5] = {lin_w, Wq, Wk, Wv, Wsk};
  int idx = blockIdx.x * 256 + threadIdx.x;
  if (idx < 5 * 4096) {
    int s = idx >> 12, r = idx & 4095;
    int j = r >> 6, c = r & 63;
    wt[(s << 12) + c * 64 + j] = (_Float16)Ws[s][j * 64 + c];
  }
}

// ---------------- K1: MFMA node projections (layouts verified in-session R8) ----------------
__global__ __launch_bounds__(256) void k_node_proj(
    const float* __restrict__ x, const _Float16* __restrict__ wt,
    const float* __restrict__ lin_b, const float* __restrict__ bq,
    const float* __restrict__ bk, const float* __restrict__ bv,
    const float* __restrict__ bsk, const float* __restrict__ be,
    float* __restrict__ q, __half2* __restrict__ kvp,
    float* __restrict__ skipout, int N) {
  __shared__ _Float16 H[4][16 * 72];
  const int tid = threadIdx.x;
  const int lane = tid & 63;
  const int wv = tid >> 6;
  const int mrow = lane & 15;
  const int kgrp = lane >> 4;
  const float invs = 0.17677669529663687f;  // 1/sqrt(32)
  float b_lin[4], b_q[4], b_k[4], b_v[4], b_sk[4];
#pragma unroll
  for (int nt = 0; nt < 4; ++nt) {
    const int cc = nt * 16 + mrow;
    b_lin[nt] = lin_b[cc];
    b_q[nt] = bq[cc];
    b_k[nt] = bk[cc] + be[cc];
    b_v[nt] = bv[cc] + be[cc];
    b_sk[nt] = bsk[cc];
  }
  _Float16* Hw = H[wv];
  const int ntiles = (N + 63) >> 6;
  for (int tile = blockIdx.x; tile < ntiles; tile += gridDim.x) {
    const int base = tile << 6;
    const int rowA = base + wv * 16 + mrow;
    const int rclamp = (rowA < N) ? rowA : (N - 1);
    const float* xr = x + (size_t)rclamp * 64 + kgrp * 8;
    const float4 u0 = *(const float4*)xr;
    const float4 u1 = *(const float4*)(xr + 4);
    const float4 u2 = *(const float4*)(xr + 32);
    const float4 u3 = *(const float4*)(xr + 36);
    const f16x8 a0 = {(_Float16)u0.x, (_Float16)u0.y, (_Float16)u0.z, (_Float16)u0.w,
                      (_Float16)u1.x, (_Float16)u1.y, (_Float16)u1.z, (_Float16)u1.w};
    const f16x8 a1 = {(_Float16)u2.x, (_Float16)u2.y, (_Float16)u2.z, (_Float16)u2.w,
                      (_Float16)u3.x, (_Float16)u3.y, (_Float16)u3.z, (_Float16)u3.w};
#pragma unroll
    for (int nt = 0; nt < 4; ++nt) {
      const _Float16* wb0 = wt + (nt * 16 + mrow) * 64 + kgrp * 8;
      const f16x8 B0 = *(const f16x8*)wb0;
      const f16x8 B1 = *(const f16x8*)(wb0 + 32);
      f32x4 C = {0.f, 0.f, 0.f, 0.f};
      C = __builtin_amdgcn_mfma_f32_16x16x32_f16(a0, B0, C, 0, 0, 0);
      C = __builtin_amdgcn_mfma_f32_16x16x32_f16(a1, B1, C, 0, 0, 0);
#pragma unroll
      for (int r = 0; r < 4; ++r) {
        const float hval = fmaxf(C[r] + b_lin[nt], 0.f);
        Hw[(kgrp * 4 + r) * 72 + nt * 16 + mrow] = (_Float16)hval;
      }
    }
    const f16x8 ha0 = *(const f16x8*)(Hw + mrow * 72 + kgrp * 8);
    const f16x8 ha1 = *(const f16x8*)(Hw + mrow * 72 + 32 + kgrp * 8);
    const int orow0 = base + wv * 16 + kgrp * 4;
#pragma unroll
    for (int nt = 0; nt < 4; ++nt) {
      const _Float16* wb0 = wt + 4096 + (nt * 16 + mrow) * 64 + kgrp * 8;
      const f16x8 B0 = *(const f16x8*)wb0;
      const f16x8 B1 = *(const f16x8*)(wb0 + 32);
      f32x4 C = {0.f, 0.f, 0.f, 0.f};
      C = __builtin_amdgcn_mfma_f32_16x16x32_f16(ha0, B0, C, 0, 0, 0);
      C = __builtin_amdgcn_mfma_f32_16x16x32_f16(ha1, B1, C, 0, 0, 0);
#pragma unroll
      for (int r = 0; r < 4; ++r) {
        const int orow = orow0 + r;
        if (orow < N) q[(size_t)orow * 64 + nt * 16 + mrow] = (C[r] + b_q[nt]) * invs;
      }
    }
#pragma unroll
    for (int nt = 0; nt < 4; ++nt) {
      const _Float16* wk0 = wt + 2 * 4096 + (nt * 16 + mrow) * 64 + kgrp * 8;
      const _Float16* wv0 = wt + 3 * 4096 + (nt * 16 + mrow) * 64 + kgrp * 8;
      const f16x8 Bk0 = *(const f16x8*)wk0;
      const f16x8 Bk1 = *(const f16x8*)(wk0 + 32);
      const f16x8 Bv0 = *(const f16x8*)wv0;
      const f16x8 Bv1 = *(const f16x8*)(wv0 + 32);
      f32x4 Ck = {0.f, 0.f, 0.f, 0.f};
      f32x4 Cv = {0.f, 0.f, 0.f, 0.f};
      Ck = __builtin_amdgcn_mfma_f32_16x16x32_f16(ha0, Bk0, Ck, 0, 0, 0);
      Ck = __builtin_amdgcn_mfma_f32_16x16x32_f16(ha1, Bk1, Ck, 0, 0, 0);
      Cv = __builtin_amdgcn_mfma_f32_16x16x32_f16(ha0, Bv0, Cv, 0, 0, 0);
      Cv = __builtin_amdgcn_mfma_f32_16x16x32_f16(ha1, Bv1, Cv, 0, 0, 0);
#pragma unroll
      for (int r = 0; r < 4; ++r) {
        const int orow = orow0 + r;
        if (orow < N)
          kvp[(size_t)orow * 64 + nt * 16 + mrow] =
              __halves2half2(__float2half_rn(Ck[r] + b_k[nt]), __float2half_rn(Cv[r] + b_v[nt]));
      }
    }
#pragma unroll
    for (int nt = 0; nt < 4; ++nt) {
      const _Float16* wb0 = wt + 4 * 4096 + (nt * 16 + mrow) * 64 + kgrp * 8;
      const f16x8 B0 = *(const f16x8*)wb0;
      const f16x8 B1 = *(const f16x8*)(wb0 + 32);
      f32x4 C = {0.f, 0.f, 0.f, 0.f};
      C = __builtin_amdgcn_mfma_f32_16x16x32_f16(ha0, B0, C, 0, 0, 0);
      C = __builtin_amdgcn_mfma_f32_16x16x32_f16(ha1, B1, C, 0, 0, 0);
#pragma unroll
      for (int r = 0; r < 4; ++r) {
        const int orow = orow0 + r;
        if (orow < N) skipout[(size_t)orow * 64 + nt * 16 + mrow] = C[r] + b_sk[nt];
      }
    }
  }
}

// ---------------- CSR build ----------------
__global__ __launch_bounds__(256) void k_hist(const int* __restrict__ ei, int* __restrict__ counts, int E) {
  int i = blockIdx.x * 256 + threadIdx.x;
  if (i < E) atomicAdd(&counts[ei[E + i]], 1);
}

__global__ __launch_bounds__(256) void k_scan1(const int* __restrict__ counts, int* __restrict__ excl,
                                               int* __restrict__ bsum, int N) {
  __shared__ int s[256];
  const int t = threadIdx.x;
  const int idx = blockIdx.x * 256 + t;
  int val = (idx < N) ? counts[idx] : 0;
  s[t] = val;
  __syncthreads();
  for (int d = 1; d < 256; d <<= 1) {
    int add = (t >= d) ? s[t - d] : 0;
    __syncthreads();
    s[t] += add;
    __syncthreads();
  }
  if (idx < N) excl[idx] = s[t] - val;
  if (t == 255) bsum[blockIdx.x] = s[255];
}

__global__ __launch_bounds__(1024) void k_scan2(int* __restrict__ bsum, int B) {
  __shared__ int sm[1024];
  const int t = threadIdx.x;
  if (B <= 1024) {
    int val = (t < B) ? bsum[t] : 0;
    sm[t] = val;
    __syncthreads();
    for (int d = 1; d < 1024; d <<= 1) {
      int add = (t >= d) ? sm[t - d] : 0;
      __syncthreads();
      sm[t] += add;
      __syncthreads();
    }
    if (t < B) bsum[t] = sm[t] - val;  // exclusive
  } else if (t == 0) {
    int acc = 0;
    for (int i = 0; i < B; ++i) { int tt = bsum[i]; bsum[i] = acc; acc += tt; }
  }
}

__global__ __launch_bounds__(256) void k_scan3(const int* __restrict__ bsum, int* __restrict__ rowptr,
                                               int* __restrict__ next, int N, int E) {
  int i = blockIdx.x * 256 + threadIdx.x;
  if (i < N) {
    int r = rowptr[i] + bsum[i >> 8];
    rowptr[i] = r;
    next[i] = r;
  }
  if (i == 0) rowptr[N] = E;
}

__global__ __launch_bounds__(256) void k_fill(const int* __restrict__ ei,
                                              const float* __restrict__ node_time,
                                              const float* __restrict__ edge_time,
                                              int* __restrict__ next, int2* __restrict__ er, int E) {
  int e = blockIdx.x * 256 + threadIdx.x;
  if (e < E) {
    int s = ei[e], d = ei[E + e];
    int pos = atomicAdd(&next[d], 1);
    er[pos] = make_int2(s, __float_as_int(node_time[s] - edge_time[e]));
  }
}

// ---------------- K2: CSR gather + batched two-pass online softmax aggregate ----------------
// R8 structure (best measured: 143 us) with the 5-step ds_swizzle butterfly replaced by a
// DPP ring-rotation reduction (4 VALU adds + 1 swizzle) — LDS-pipe ops per chunk 80 -> 16.
__global__ __launch_bounds__(256) void k_aggregate(
    const int* __restrict__ rowptr, const int2* __restrict__ er,
    const float* __restrict__ q, const unsigned* __restrict__ kvu,
    const float* __restrict__ time_w, const float* __restrict__ time_b,
    const float* __restrict__ We,
    float* __restrict__ h1, int N) {
  __shared__ float swS[4][64];
  const int tid = threadIdx.x;
  const int c = tid & 63;
  const int wv = tid >> 6;
  const float INV2PI = 0.15915494309189535f;
  float wcol[32], Gw[32];
#pragma unroll
  for (int j = 0; j < 32; ++j) wcol[j] = We[j * 64 + c];
#pragma unroll
  for (int j = 0; j < 32; ++j) Gw[j] = We[(c & 31) * 64 + (c & 32) + j];
  const float tw = time_w[c & 31] * INV2PI;
  const float tb = time_b[c & 31] * INV2PI;
  const int h32 = c & 32;
  const int n0 = blockIdx.x * 4 + wv;
  const int nstride = gridDim.x * 4;
  for (int n = n0; n < N; n += nstride) {
    const int start = rowptr[n];
    const int end = rowptr[n + 1];
    const float skipv = h1[(size_t)n * 64 + c];  // prefetch staged skip early
    const float qc = q[(size_t)n * 64 + c];      // pre-scaled by 1/sqrt(32)
    swS[wv][c] = qc;
    float Gc = 0.f;
#pragma unroll
    for (int j = 0; j < 32; ++j) Gc = fmaf(swS[wv][h32 | j], Gw[j], Gc);
    float m = -1e30f, den = 0.f, num = 0.f, S = 0.f;
    for (int ce = start; ce < end; ce += 16) {
      const int cnt = (end - ce < 16) ? (end - ce) : 16;
      // ---- issue phase: 16 uniform er loads + 16 coalesced kv gathers, all in flight ----
      int src_[16];
      float rr_[16];
#pragma unroll
      for (int i = 0; i < 16; ++i) {
        const int ee = ce + ((i < cnt) ? i : cnt - 1);
        const int2 a = er[ee];
        src_[i] = a.x;
        rr_[i] = __int_as_float(a.y);
      }
      unsigned kvr[16];
#pragma unroll
      for (int i = 0; i < 16; ++i) kvr[i] = kvu[(size_t)src_[i] * 64 + c];
      // ---- pass 1: 16 independent partial products + DPP ring reductions ----
      float rv_[16], p[16];
#pragma unroll
      for (int i = 0; i < 16; ++i) {
        float ang = fmaf(rr_[i], tw, tb);
        ang = ang - floorf(ang);
        rv_[i] = __builtin_amdgcn_cosf(ang);   // cos(2*pi*ang)
        const __half2 h2 = *(const __half2*)&kvr[i];
        p[i] = fmaf(rv_[i], Gc, qc * __half2float(h2.x));
      }
#pragma unroll
      for (int i = 0; i < 16; ++i) p[i] = hsum32_dpp(p[i]);
#pragma unroll
      for (int i = 0; i < 16; ++i)
        if (i >= cnt) p[i] = -1e30f;           // mask padded duplicates
      // ---- fold chunk max, rescale state once ----
      float cm = p[0];
#pragma unroll
      for (int i = 1; i < 16; ++i) cm = fmaxf(cm, p[i]);
      const float mn = fmaxf(m, cm);
      const float sc = __expf(m - mn);
      num *= sc; den *= sc; S *= sc; m = mn;
      // ---- pass 2: 16 independent exp + FMA updates ----
#pragma unroll
      for (int i = 0; i < 16; ++i) {
        if (i < cnt) {
          const float ea = __expf(p[i] - m);
          const __half2 h2 = *(const __half2*)&kvr[i];
          num = fmaf(ea, __half2float(h2.y), num);
          S = fmaf(ea, rv_[i], S);
          den += ea;
        }
      }
    }
    // e-projection contribution: econ[c] = sum_j We[j,c] * S[h32 + j]
    swS[wv][c] = S;
    float econ = 0.f;
#pragma unroll
    for (int j = 0; j < 32; ++j) econ = fmaf(swS[wv][h32 | j], wcol[j], econ);
    const float agg = (num + econ) / (den + 1e-16f);
    h1[(size_t)n * 64 + c] = agg + skipv;
  }
}

// ---------------- K4: epilogue (context attention + combine + out + log_softmax) ----------------
__global__ __launch_bounds__(256) void k_epilogue(
    const float* __restrict__ t_int, const float* __restrict__ deg,
    const float* __restrict__ cbuf,
    const float* __restrict__ wx_w, const float* __restrict__ wx_b,
    const float* __restrict__ comb_w, const float* __restrict__ comb_b,
    const float* __restrict__ out_w, const float* __restrict__ out_b,
    const int* __restrict__ y, const unsigned char* __restrict__ maskb,
    float* __restrict__ out, int N) {
  __shared__ float sh[4][64];
  const int tid = threadIdx.x;
  const int c = tid & 63;
  const int wv = tid >> 6;
  float wxreg[64], cbreg[64];
#pragma unroll
  for (int j = 0; j < 64; ++j) { wxreg[j] = wx_w[j * 64 + c]; cbreg[j] = comb_w[j * 64 + c]; }
  const float A0 = cbuf[c], B0 = cbuf[64 + c], A1 = cbuf[128 + c], B1 = cbuf[192 + c];
  const float P0 = cbuf[256 + c], Q0 = cbuf[320 + c], P1 = cbuf[384 + c], Q1 = cbuf[448 + c];
  const float wxb = wx_b[c], cbb = comb_b[c];
  const float ow0 = out_w[c * 2 + 0], ow1 = out_w[c * 2 + 1];
  const float ob0 = out_b[0], ob1 = out_b[1];
  const size_t O1 = (size_t)N * 64;
  const size_t O2 = O1 + (size_t)N * 2;
  const size_t O3 = O2 + (size_t)N;
  const int ngroups = (N + 3) >> 2;
  for (int g = blockIdx.x; g < ngroups; g += gridDim.x) {
    const int n = g * 4 + wv;
    const bool act = n < N;
    float h1a = 0.f, ti = 0.f, dg = 0.f;
    if (act) {
      h1a = out[(size_t)n * 64 + c];
      ti = t_int[n];
      dg = deg[n];
    }
    sh[wv][c] = h1a;
    __syncthreads();
    const float4* hr = (const float4*)&sh[wv][0];
    float xp = wxb;
    float acc = cbb;
#pragma unroll
    for (int j4 = 0; j4 < 16; ++j4) {
      float4 hv = hr[j4];
      xp  = fmaf(hv.x, wxreg[4 * j4 + 0], xp);
      xp  = fmaf(hv.y, wxreg[4 * j4 + 1], xp);
      xp  = fmaf(hv.z, wxreg[4 * j4 + 2], xp);
      xp  = fmaf(hv.w, wxreg[4 * j4 + 3], xp);
      acc = fmaf(hv.x, cbreg[4 * j4 + 0], acc);
      acc = fmaf(hv.y, cbreg[4 * j4 + 1], acc);
      acc = fmaf(hv.z, cbreg[4 * j4 + 2], acc);
      acc = fmaf(hv.w, cbreg[4 * j4 + 3], acc);
    }
    xp = tanhf(xp);
    const float ep0 = tanhf(fmaf(ti, A0, B0));
    const float ep1 = tanhf(fmaf(dg, A1, B1));
    float d0 = ep0 * xp, d1 = ep1 * xp;
#pragma unroll
    for (int msk = 32; msk >= 1; msk >>= 1) { d0 += __shfl_xor(d0, msk, 64); d1 += __shfl_xor(d1, msk, 64); }
    const float mx = fmaxf(d0, d1);
    const float e0 = expf(d0 - mx), e1 = expf(d1 - mx);
    const float sden = e0 + e1;
    const float s0 = e0 / sden, s1 = e1 / sden;
    acc = fmaf(s0, fmaf(ti, P0, Q0), acc);
    acc = fmaf(s1, fmaf(dg, P1, Q1), acc);
    float z0 = acc * ow0, z1 = acc * ow1;
#pragma unroll
    for (int msk = 32; msk >= 1; msk >>= 1) { z0 += __shfl_xor(z0, msk, 64); z1 += __shfl_xor(z1, msk, 64); }
    if (act) {
      out[(size_t)n * 64 + c] = acc;
      if (c == 0) {
        z0 += ob0; z1 += ob1;
        const float mz = fmaxf(z0, z1);
        const float lse = mz + logf(expf(z0 - mz) + expf(z1 - mz));
        out[O1 + (size_t)n * 2 + 0] = z0 - lse;
        out[O1 + (size_t)n * 2 + 1] = z1 - lse;
        out[O2 + (size_t)n] = (float)y[n];
        out[O3 + (size_t)n] = mask_val(maskb, n);
      }
    }
    __syncthreads();
  }
}

extern "C" void kernel_launch(void* const* d_in, const int* in_sizes, int n_in,
                              void* d_out, int out_size, void* d_ws, size_t ws_size,
                              hipStream_t stream) {
  const float* x          = (const float*)d_in[0];
  const int*   ei         = (const int*)d_in[1];
  const float* node_time  = (const float*)d_in[2];
  const float* edge_time  = (const float*)d_in[3];
  const float* nmoti      = (const float*)d_in[4];
  const float* nod        = (const float*)d_in[5];
  const int*   y          = (const int*)d_in[6];
  const unsigned char* mask = (const unsigned char*)d_in[7];
  const float* time_w = (const float*)d_in[8];
  const float* time_b = (const float*)d_in[9];
  const float* tf_w   = (const float*)d_in[10];
  const float* tf_b   = (const float*)d_in[11];
  const float* deg_w  = (const float*)d_in[12];
  const float* deg_b  = (const float*)d_in[13];
  const float* lin_w  = (const float*)d_in[14];
  const float* lin_b  = (const float*)d_in[15];
  const float* Wq     = (const float*)d_in[16];
  const float* bq     = (const float*)d_in[17];
  const float* Wk     = (const float*)d_in[18];
  const float* bk     = (const float*)d_in[19];
  const float* Wv     = (const float*)d_in[20];
  const float* bv     = (const float*)d_in[21];
  const float* We     = (const float*)d_in[22];
  const float* be     = (const float*)d_in[23];
  const float* Wsk    = (const float*)d_in[24];
  const float* bsk    = (const float*)d_in[25];
  const float* wenc_w = (const float*)d_in[26];
  const float* wenc_b = (const float*)d_in[27];
  const float* wx_w   = (const float*)d_in[28];
  const float* wx_b   = (const float*)d_in[29];
  const float* comb_w = (const float*)d_in[30];
  const float* comb_b = (const float*)d_in[31];
  const float* out_w  = (const float*)d_in[32];
  const float* out_b  = (const float*)d_in[33];

  const int N = in_sizes[2];   // node_time
  const int E = in_sizes[3];   // edge_time
  const size_t N64 = (size_t)N * 64;

  float*    q    = (float*)d_ws;
  __half2*  kvp  = (__half2*)(q + N64);       // N64 half2 = N64 * 4B
  int2*     er   = (int2*)((char*)kvp + N64 * sizeof(__half2));
  int*      counts = (int*)(er + E);
  int*      rowptr = counts + N;              // N+1 ints
  int*      next   = rowptr + N + 1;
  int*      bsum   = next + N;                // ceil(N/256) ints (padded)
  float*    cbuf   = (float*)(bsum + 4096);
  _Float16* wt     = (_Float16*)(cbuf + 512); // 5 * 4096 fp16
  float*    outf   = (float*)d_out;
  float*    skip   = outf;  // stage skip in d_out[0:N*64)

  const int B = (N + 255) / 256;

  hipMemsetAsync(counts, 0, (size_t)N * sizeof(int), stream);

  k_precompute<<<1, 64, 0, stream>>>(tf_w, tf_b, deg_w, deg_b, wenc_w, wenc_b, comb_w, cbuf);
  k_wcvt<<<80, 256, 0, stream>>>(lin_w, Wq, Wk, Wv, Wsk, wt);

  const int ntiles = (N + 63) >> 6;
  k_node_proj<<<ntiles, 256, 0, stream>>>(x, wt, lin_b, bq, bk, bv, bsk, be,
                                          q, kvp, skip, N);

  const int EB = (E + 255) / 256;
  k_hist<<<EB, 256, 0, stream>>>(ei, counts, E);
  k_scan1<<<B, 256, 0, stream>>>(counts, rowptr, bsum, N);
  k_scan2<<<1, 1024, 0, stream>>>(bsum, B);
  k_scan3<<<B, 256, 0, stream>>>(bsum, rowptr, next, N, E);
  k_fill<<<EB, 256, 0, stream>>>(ei, node_time, edge_time, next, er, E);

  // persistent grid: 1024 blocks = 4 blocks/CU (16 waves/CU), ~24 nodes/wave
  int agb = 1024;
  if (agb > (N + 3) / 4) agb = (N + 3) / 4;
  k_aggregate<<<agb, 256, 0, stream>>>(rowptr, er, q, (const unsigned*)kvp,
                                       time_w, time_b, We, outf, N);

  k_epilogue<<<2048, 256, 0, stream>>>(nmoti, nod, cbuf, wx_w, wx_b,
                                       comb_w, comb_b, out_w, out_b, y, mask, outf, N);
}